// Round 1
// baseline (540.022 us; speedup 1.0000x reference)
//
#include <hip/hip_runtime.h>
#include <hip/hip_bf16.h>

#define ALPHA 0.1f

// ---------------- edge preprocessing ----------------

__global__ void deg_kernel(const int* __restrict__ ei, int* __restrict__ cnt, int E) {
    int e = blockIdx.x * blockDim.x + threadIdx.x;
    if (e >= E) return;
    atomicAdd(&cnt[ei[E + e]], 1);
}

__global__ void dinv_kernel(const int* __restrict__ cnt, float* __restrict__ dinv, int N) {
    int i = blockIdx.x * blockDim.x + threadIdx.x;
    if (i >= N) return;
    // deg = edge-count + 1 (self loop), always >= 1
    dinv[i] = 1.0f / sqrtf((float)(cnt[i] + 1));
}

// exclusive scan of cnt[0..n) -> row_off[0..n], single block of 1024 threads
__global__ void scan_kernel(const int* __restrict__ cnt, int* __restrict__ row_off, int n) {
    constexpr int T = 1024;
    __shared__ int part[T];
    int tid = threadIdx.x;
    int chunk = (n + T - 1) / T;
    int lo = tid * chunk;
    int hi = lo + chunk; if (hi > n) hi = n;
    int s = 0;
    for (int i = lo; i < hi; ++i) s += cnt[i];
    part[tid] = s;
    __syncthreads();
    for (int off = 1; off < T; off <<= 1) {
        int t = (tid >= off) ? part[tid - off] : 0;
        __syncthreads();
        part[tid] += t;
        __syncthreads();
    }
    int excl = part[tid] - s;   // sum of all chunks before mine
    for (int i = lo; i < hi; ++i) { row_off[i] = excl; excl += cnt[i]; }
    if (tid == T - 1) row_off[n] = part[T - 1];
}

__global__ void fill_kernel(const int* __restrict__ ei, const int* __restrict__ row_off,
                            int* __restrict__ fill, int* __restrict__ col, int E) {
    int e = blockIdx.x * blockDim.x + threadIdx.x;
    if (e >= E) return;
    int s = ei[e], d = ei[E + e];
    int pos = atomicAdd(&fill[d], 1);
    col[row_off[d] + pos] = s;
}

// ---------------- aggregation: one wave per node, 128 feats = 64 lanes x float2 ----------------

__global__ void agg_kernel(const float2* __restrict__ x2, const int* __restrict__ col,
                           const int* __restrict__ row_off, const float* __restrict__ dinv,
                           float2* __restrict__ agg2, int N) {
    int w = (blockIdx.x * blockDim.x + threadIdx.x) >> 6;
    int lane = threadIdx.x & 63;
    if (w >= N) return;
    float di = dinv[w];
    float2 xv = x2[(size_t)w * 64 + lane];
    float wself = di * di;
    float2 acc = { wself * xv.x, wself * xv.y };
    int s = row_off[w], e = row_off[w + 1];
    for (int j = s; j < e; ++j) {
        int src = col[j];
        float wt = dinv[src] * di;
        float2 v = x2[(size_t)src * 64 + lane];
        acc.x += wt * v.x;
        acc.y += wt * v.y;
    }
    agg2[(size_t)w * 64 + lane] = acc;
}

// ---------------- fold W_gcn@W1 -> Wc [128,256], bc = b_gcn@W1 + b1 ----------------

__global__ void wcbc_kernel(const float* __restrict__ Wg, const float* __restrict__ bg,
                            const float* __restrict__ W1, const float* __restrict__ b1,
                            float* __restrict__ Wc, float* __restrict__ bc) {
    int n = threadIdx.x;      // 0..255
    int m = blockIdx.x;       // 0..128 (128 -> bias row)
    if (m < 128) {
        float acc = 0.f;
        for (int k = 0; k < 512; ++k) acc += Wg[m * 512 + k] * W1[k * 256 + n];
        Wc[m * 256 + n] = acc;
    } else {
        float acc = b1[n];
        for (int k = 0; k < 512; ++k) acc += bg[k] * W1[k * 256 + n];
        bc[n] = acc;
    }
}

// ---------------- fp32 register-tiled GEMM: C = act(A[M,K] @ B[K,N] + bias) ----------------
// block 256 threads (16x16), tile 128x128, micro 8x8, K-chunk 32

template <bool LEAKY>
__global__ __launch_bounds__(256) void gemm_k(const float* __restrict__ A, const float* __restrict__ B,
                                              const float* __restrict__ bias, float* __restrict__ C,
                                              int M, int N, int K) {
    constexpr int BM = 128, BN = 128, KC = 32, PAD = 4;
    __shared__ float As[KC][BM + PAD];   // transposed: As[k][m]
    __shared__ float Bs[KC][BN];
    int tid = threadIdx.x;
    int tm = tid >> 4;          // 0..15 -> rows tm*8..tm*8+7
    int tn = tid & 15;          // 0..15 -> cols tn*8..tn*8+7
    int m0 = blockIdx.x * BM, n0 = blockIdx.y * BN;

    float acc[8][8] = {};

    for (int k0 = 0; k0 < K; k0 += KC) {
        // stage A (transposed into LDS): 128x32 floats, float4 along k
#pragma unroll
        for (int i = 0; i < 4; ++i) {
            int lin = tid + i * 256;
            int kq = lin & 7;          // 0..7  (k = 4*kq)
            int m  = lin >> 3;         // 0..127
            int gm = m0 + m; if (gm >= M) gm = M - 1;
            float4 a = *reinterpret_cast<const float4*>(&A[(size_t)gm * K + k0 + kq * 4]);
            int kk = kq * 4;
            As[kk + 0][m] = a.x; As[kk + 1][m] = a.y;
            As[kk + 2][m] = a.z; As[kk + 3][m] = a.w;
        }
        // stage B: 32x128 floats, float4 along n
#pragma unroll
        for (int i = 0; i < 4; ++i) {
            int lin = tid + i * 256;
            int nq = lin & 31;         // 0..31
            int k  = lin >> 5;         // 0..31
            float4 b = *reinterpret_cast<const float4*>(&B[(size_t)(k0 + k) * N + n0 + nq * 4]);
            *reinterpret_cast<float4*>(&Bs[k][nq * 4]) = b;
        }
        __syncthreads();
#pragma unroll
        for (int kk = 0; kk < KC; ++kk) {
            float a[8], b[8];
            *(float4*)&a[0] = *(const float4*)&As[kk][tm * 8];
            *(float4*)&a[4] = *(const float4*)&As[kk][tm * 8 + 4];
            *(float4*)&b[0] = *(const float4*)&Bs[kk][tn * 8];
            *(float4*)&b[4] = *(const float4*)&Bs[kk][tn * 8 + 4];
#pragma unroll
            for (int i = 0; i < 8; ++i)
#pragma unroll
                for (int j = 0; j < 8; ++j)
                    acc[i][j] += a[i] * b[j];
        }
        __syncthreads();
    }

#pragma unroll
    for (int i = 0; i < 8; ++i) {
        int gm = m0 + tm * 8 + i;
        if (gm >= M) continue;
        float v[8];
#pragma unroll
        for (int j = 0; j < 8; ++j) {
            int gn = n0 + tn * 8 + j;
            float t = acc[i][j] + bias[gn];
            if (LEAKY) t = (t > 0.f) ? t : ALPHA * t;
            v[j] = t;
        }
        *(float4*)&C[(size_t)gm * N + n0 + tn * 8]     = *(float4*)&v[0];
        *(float4*)&C[(size_t)gm * N + n0 + tn * 8 + 4] = *(float4*)&v[4];
    }
}

// ---------------- output head: out[m] = h[m,:] . Wout + b, one wave per row ----------------

__global__ void out_kernel(const float* __restrict__ h, const float* __restrict__ wout,
                           const float* __restrict__ bout, float* __restrict__ out, int M) {
    int w = (blockIdx.x * blockDim.x + threadIdx.x) >> 6;
    int lane = threadIdx.x & 63;
    if (w >= M) return;
    float4 hv = *reinterpret_cast<const float4*>(&h[(size_t)w * 256 + lane * 4]);
    float4 wv = *reinterpret_cast<const float4*>(&wout[lane * 4]);
    float s = hv.x * wv.x + hv.y * wv.y + hv.z * wv.z + hv.w * wv.w;
#pragma unroll
    for (int off = 32; off; off >>= 1) s += __shfl_down(s, off, 64);
    if (lane == 0) out[w] = s + bout[0];
}

// ---------------- launch ----------------

extern "C" void kernel_launch(void* const* d_in, const int* in_sizes, int n_in,
                              void* d_out, int out_size, void* d_ws, size_t ws_size,
                              hipStream_t stream) {
    const float* x  = (const float*)d_in[0];
    const int*   ei = (const int*)d_in[1];
    const float* Wg = (const float*)d_in[2];
    const float* bg = (const float*)d_in[3];
    const float* W1 = (const float*)d_in[4];
    const float* b1 = (const float*)d_in[5];
    const float* W2 = (const float*)d_in[6];
    const float* b2 = (const float*)d_in[7];
    const float* W3 = (const float*)d_in[8];
    const float* b3 = (const float*)d_in[9];
    const float* Wo = (const float*)d_in[10];
    const float* bo = (const float*)d_in[11];
    float* out = (float*)d_out;

    const int N = in_sizes[0] / 128;   // 50000
    const int E = in_sizes[1] / 2;     // 800000

    char* ws = (char*)d_ws;
    float* agg = (float*)ws;  ws += (size_t)N * 128 * 4;
    float* h1  = (float*)ws;  ws += (size_t)N * 256 * 4;
    float* h2  = (float*)ws;  ws += (size_t)N * 256 * 4;
    int* col   = (int*)ws;    ws += (size_t)E * 4;
    int* cnt   = (int*)ws;    ws += (size_t)N * 4;
    int* fill  = (int*)ws;    ws += (size_t)N * 4;   // cnt & fill contiguous -> one memset
    int* roff  = (int*)ws;    ws += (size_t)(N + 64) * 4;
    float* dinv= (float*)ws;  ws += (size_t)N * 4;
    float* Wc  = (float*)ws;  ws += 128 * 256 * 4;
    float* bc  = (float*)ws;  ws += 256 * 4;

    hipMemsetAsync(cnt, 0, (size_t)N * 8, stream);   // cnt + fill

    deg_kernel <<<(E + 255) / 256, 256, 0, stream>>>(ei, cnt, E);
    dinv_kernel<<<(N + 255) / 256, 256, 0, stream>>>(cnt, dinv, N);
    scan_kernel<<<1, 1024, 0, stream>>>(cnt, roff, N);
    fill_kernel<<<(E + 255) / 256, 256, 0, stream>>>(ei, roff, fill, col, E);
    agg_kernel <<<(N + 3) / 4, 256, 0, stream>>>((const float2*)x, col, roff, dinv, (float2*)agg, N);
    wcbc_kernel<<<129, 256, 0, stream>>>(Wg, bg, W1, b1, Wc, bc);

    dim3 g((N + 127) / 128, 2);
    gemm_k<true><<<g, 256, 0, stream>>>(agg, Wc, bc, h1, N, 256, 128);
    gemm_k<true><<<g, 256, 0, stream>>>(h1, W2, b2, h2, N, 256, 256);
    gemm_k<true><<<g, 256, 0, stream>>>(h2, W3, b3, h1, N, 256, 256);  // h1 reused for h3

    out_kernel<<<(N + 3) / 4, 256, 0, stream>>>(h1, Wo, bo, out, N);
}

// Round 2
// 384.580 us; speedup vs baseline: 1.4042x; 1.4042x over previous
//
#include <hip/hip_runtime.h>
#include <hip/hip_bf16.h>

#define ALPHA 0.1f

using bf16x8 = __attribute__((ext_vector_type(8))) short;
using f32x4  = __attribute__((ext_vector_type(4))) float;

__device__ __forceinline__ unsigned short f2bf(float f) {
    unsigned u = __builtin_bit_cast(unsigned, f);
    u += 0x7fff + ((u >> 16) & 1);               // round-to-nearest-even
    return (unsigned short)(u >> 16);
}
__device__ __forceinline__ float bf2f(unsigned short h) {
    unsigned u = ((unsigned)h) << 16;
    return __builtin_bit_cast(float, u);
}

// ---------------- edge preprocessing ----------------

__global__ void deg_kernel(const int* __restrict__ ei, int* __restrict__ cnt, int E) {
    int e = blockIdx.x * blockDim.x + threadIdx.x;
    if (e >= E) return;
    atomicAdd(&cnt[ei[E + e]], 1);
}

__global__ void dinv_kernel(const int* __restrict__ cnt, float* __restrict__ dinv, int N) {
    int i = blockIdx.x * blockDim.x + threadIdx.x;
    if (i >= N) return;
    dinv[i] = 1.0f / sqrtf((float)(cnt[i] + 1));   // +1 self loop
}

__global__ void scan_kernel(const int* __restrict__ cnt, int* __restrict__ row_off, int n) {
    constexpr int T = 1024;
    __shared__ int part[T];
    int tid = threadIdx.x;
    int chunk = (n + T - 1) / T;
    int lo = tid * chunk;
    int hi = lo + chunk; if (hi > n) hi = n;
    int s = 0;
    for (int i = lo; i < hi; ++i) s += cnt[i];
    part[tid] = s;
    __syncthreads();
    for (int off = 1; off < T; off <<= 1) {
        int t = (tid >= off) ? part[tid - off] : 0;
        __syncthreads();
        part[tid] += t;
        __syncthreads();
    }
    int excl = part[tid] - s;
    for (int i = lo; i < hi; ++i) { row_off[i] = excl; excl += cnt[i]; }
    if (tid == T - 1) row_off[n] = part[T - 1];
}

__global__ void fill_kernel(const int* __restrict__ ei, const int* __restrict__ row_off,
                            int* __restrict__ fill, int* __restrict__ col, int E) {
    int e = blockIdx.x * blockDim.x + threadIdx.x;
    if (e >= E) return;
    int s = ei[e], d = ei[E + e];
    int pos = atomicAdd(&fill[d], 1);
    col[row_off[d] + pos] = s;
}

// ---------------- aggregation: one wave per node ----------------

__global__ void agg_kernel(const float2* __restrict__ x2, const int* __restrict__ col,
                           const int* __restrict__ row_off, const float* __restrict__ dinv,
                           float2* __restrict__ agg2, int N) {
    int w = (blockIdx.x * blockDim.x + threadIdx.x) >> 6;
    int lane = threadIdx.x & 63;
    if (w >= N) return;
    float di = dinv[w];
    float2 xv = x2[(size_t)w * 64 + lane];
    float wself = di * di;
    float2 acc = { wself * xv.x, wself * xv.y };
    int s = row_off[w], e = row_off[w + 1];
    for (int j = s; j < e; ++j) {
        int src = col[j];
        float wt = dinv[src] * di;
        float2 v = x2[(size_t)src * 64 + lane];
        acc.x += wt * v.x;
        acc.y += wt * v.y;
    }
    agg2[(size_t)w * 64 + lane] = acc;
}

// ---------------- fold W_gcn@W1 -> Wc [128,256], bc = b_gcn@W1 + b1 ----------------

__global__ void wcbc_kernel(const float* __restrict__ Wg, const float* __restrict__ bg,
                            const float* __restrict__ W1, const float* __restrict__ b1,
                            float* __restrict__ Wc, float* __restrict__ bc) {
    int n = threadIdx.x;
    int m = blockIdx.x;
    if (m < 128) {
        float acc = 0.f;
        for (int k = 0; k < 512; ++k) acc += Wg[m * 512 + k] * W1[k * 256 + n];
        Wc[m * 256 + n] = acc;
    } else {
        float acc = b1[n];
        for (int k = 0; k < 512; ++k) acc += bg[k] * W1[k * 256 + n];
        bc[n] = acc;
    }
}

// ---------------- transpose+split weights: W[K][Nn] fp32 -> Wt_hi/lo [Nn][K] bf16 ----------------

__global__ void tsplit_kernel(const float* __restrict__ W, unsigned short* __restrict__ hi,
                              unsigned short* __restrict__ lo, int K, int Nn) {
    int idx = blockIdx.x * blockDim.x + threadIdx.x;
    if (idx >= K * Nn) return;
    int n = idx / K, k = idx - n * K;       // output coalesced along k
    float v = W[k * Nn + n];
    unsigned short h = f2bf(v);
    hi[idx] = h;
    lo[idx] = f2bf(v - bf2f(h));
}

// ---------------- split-bf16 MFMA GEMM: C = leaky(A[M,K]@B[K,256] + bias) ----------------
// 3-pass split: hi*hi + hi*lo + lo*hi  (~fp32 precision at bf16 MFMA rate)
// block = 256 thr = 4 waves (2x2), tile 128x128, wave tile 64x64 = 4x4 frags of 16x16x32

template <int KTOT, bool OUT>
__global__ __launch_bounds__(256) void gemm_mfma(
    const float* __restrict__ A, const unsigned short* __restrict__ BtHi,
    const unsigned short* __restrict__ BtLo, const float* __restrict__ bias,
    float* __restrict__ C, const float* __restrict__ wo,
    const float* __restrict__ bo, float* __restrict__ outv, int M)
{
    constexpr int BM = 128, BN = 128, BK = 32, LDT = BK + 8;   // +8 bf16 pad
    __shared__ unsigned short Ahi[BM][LDT], Alo[BM][LDT], Bhi[BN][LDT], Blo[BN][LDT];

    const int tid  = threadIdx.x;
    const int lane = tid & 63;
    const int wid  = tid >> 6;
    const int wrow = wid >> 1, wcol = wid & 1;
    const int m0 = blockIdx.x * BM, n0 = blockIdx.y * BN;
    const int l15 = lane & 15, l4 = lane >> 4;
    const int koff = l4 * 8;

    f32x4 acc[4][4] = {};

    for (int k0 = 0; k0 < KTOT; k0 += BK) {
        // ---- stage A (fp32 -> split bf16 hi/lo) ----
#pragma unroll
        for (int i = 0; i < 4; ++i) {
            int lin = tid + i * 256;
            int m = lin >> 3, c = lin & 7;
            int gm = m0 + m; if (gm >= M) gm = M - 1;
            float4 a = *reinterpret_cast<const float4*>(&A[(size_t)gm * KTOT + k0 + c * 4]);
            ushort4 h, l;
            h.x = f2bf(a.x); l.x = f2bf(a.x - bf2f(h.x));
            h.y = f2bf(a.y); l.y = f2bf(a.y - bf2f(h.y));
            h.z = f2bf(a.z); l.z = f2bf(a.z - bf2f(h.z));
            h.w = f2bf(a.w); l.w = f2bf(a.w - bf2f(h.w));
            *reinterpret_cast<ushort4*>(&Ahi[m][c * 4]) = h;
            *reinterpret_cast<ushort4*>(&Alo[m][c * 4]) = l;
        }
        // ---- stage B (pre-split bf16, plain b128 copies) ----
#pragma unroll
        for (int i = 0; i < 2; ++i) {
            int lin = tid + i * 256;
            int n = lin >> 2, s = lin & 3;
            size_t gb = (size_t)(n0 + n) * KTOT + k0 + s * 8;
            *reinterpret_cast<int4*>(&Bhi[n][s * 8]) = *reinterpret_cast<const int4*>(&BtHi[gb]);
            *reinterpret_cast<int4*>(&Blo[n][s * 8]) = *reinterpret_cast<const int4*>(&BtLo[gb]);
        }
        __syncthreads();

        bf16x8 af[4], al[4], bh[4], bl[4];
#pragma unroll
        for (int mi = 0; mi < 4; ++mi)
            af[mi] = *reinterpret_cast<const bf16x8*>(&Ahi[wrow * 64 + mi * 16 + l15][koff]);
#pragma unroll
        for (int ni = 0; ni < 4; ++ni)
            bh[ni] = *reinterpret_cast<const bf16x8*>(&Bhi[wcol * 64 + ni * 16 + l15][koff]);
#pragma unroll
        for (int mi = 0; mi < 4; ++mi)
#pragma unroll
            for (int ni = 0; ni < 4; ++ni)
                acc[mi][ni] = __builtin_amdgcn_mfma_f32_16x16x32_bf16(af[mi], bh[ni], acc[mi][ni], 0, 0, 0);
#pragma unroll
        for (int ni = 0; ni < 4; ++ni)
            bl[ni] = *reinterpret_cast<const bf16x8*>(&Blo[wcol * 64 + ni * 16 + l15][koff]);
#pragma unroll
        for (int mi = 0; mi < 4; ++mi)
#pragma unroll
            for (int ni = 0; ni < 4; ++ni)
                acc[mi][ni] = __builtin_amdgcn_mfma_f32_16x16x32_bf16(af[mi], bl[ni], acc[mi][ni], 0, 0, 0);
#pragma unroll
        for (int mi = 0; mi < 4; ++mi)
            al[mi] = *reinterpret_cast<const bf16x8*>(&Alo[wrow * 64 + mi * 16 + l15][koff]);
#pragma unroll
        for (int mi = 0; mi < 4; ++mi)
#pragma unroll
            for (int ni = 0; ni < 4; ++ni)
                acc[mi][ni] = __builtin_amdgcn_mfma_f32_16x16x32_bf16(al[mi], bh[ni], acc[mi][ni], 0, 0, 0);
        __syncthreads();
    }

    // ---- epilogue ----  C/D frag: col = lane&15, row = (lane>>4)*4 + reg  [m89]
    if (!OUT) {
#pragma unroll
        for (int mi = 0; mi < 4; ++mi) {
#pragma unroll
            for (int r = 0; r < 4; ++r) {
                int gm = m0 + wrow * 64 + mi * 16 + l4 * 4 + r;
                if (gm >= M) continue;
#pragma unroll
                for (int ni = 0; ni < 4; ++ni) {
                    int gn = n0 + wcol * 64 + ni * 16 + l15;
                    float v = acc[mi][ni][r] + bias[gn];
                    v = v > 0.f ? v : ALPHA * v;
                    C[(size_t)gm * 256 + gn] = v;
                }
            }
        }
    } else {
        // fused output head: out[m] = sum_n leaky(h3[m,n]) * wo[n]  (+ bo once)
        float bn[4], wn[4];
#pragma unroll
        for (int ni = 0; ni < 4; ++ni) {
            int gn = n0 + wcol * 64 + ni * 16 + l15;
            bn[ni] = bias[gn];
            wn[ni] = wo[gn];
        }
        float badd = (n0 == 0) ? bo[0] : 0.f;
#pragma unroll
        for (int mi = 0; mi < 4; ++mi) {
#pragma unroll
            for (int r = 0; r < 4; ++r) {
                float p = 0.f;
#pragma unroll
                for (int ni = 0; ni < 4; ++ni) {
                    float v = acc[mi][ni][r] + bn[ni];
                    v = v > 0.f ? v : ALPHA * v;
                    p += v * wn[ni];
                }
#pragma unroll
                for (int off = 1; off < 16; off <<= 1) p += __shfl_xor(p, off, 16);
                int gm = m0 + wrow * 64 + mi * 16 + l4 * 4 + r;
                if (l15 == 0 && gm < M) atomicAdd(&outv[gm], p + badd);
            }
        }
    }
}

// ---------------- launch ----------------

extern "C" void kernel_launch(void* const* d_in, const int* in_sizes, int n_in,
                              void* d_out, int out_size, void* d_ws, size_t ws_size,
                              hipStream_t stream) {
    const float* x  = (const float*)d_in[0];
    const int*   ei = (const int*)d_in[1];
    const float* Wg = (const float*)d_in[2];
    const float* bg = (const float*)d_in[3];
    const float* W1 = (const float*)d_in[4];
    const float* b1 = (const float*)d_in[5];
    const float* W2 = (const float*)d_in[6];
    const float* b2 = (const float*)d_in[7];
    const float* W3 = (const float*)d_in[8];
    const float* b3 = (const float*)d_in[9];
    const float* Wo = (const float*)d_in[10];
    const float* bo = (const float*)d_in[11];
    float* out = (float*)d_out;

    const int N = in_sizes[0] / 128;   // 50000
    const int E = in_sizes[1] / 2;     // 800000

    char* ws = (char*)d_ws;
    float* agg = (float*)ws;  ws += (size_t)N * 128 * 4;
    float* h1  = (float*)ws;  ws += (size_t)N * 256 * 4;
    float* h2  = (float*)ws;  ws += (size_t)N * 256 * 4;
    int* col   = (int*)ws;    ws += (size_t)E * 4;
    int* cnt   = (int*)ws;    ws += (size_t)N * 4;
    int* fill  = (int*)ws;    ws += (size_t)N * 4;   // cnt & fill contiguous -> one memset
    int* roff  = (int*)ws;    ws += (size_t)(N + 64) * 4;
    float* dinv= (float*)ws;  ws += (size_t)N * 4;
    float* Wc  = (float*)ws;  ws += 128 * 256 * 4;
    float* bc  = (float*)ws;  ws += 256 * 4;
    unsigned short* WcThi = (unsigned short*)ws; ws += 256 * 128 * 2;
    unsigned short* WcTlo = (unsigned short*)ws; ws += 256 * 128 * 2;
    unsigned short* W2Thi = (unsigned short*)ws; ws += 256 * 256 * 2;
    unsigned short* W2Tlo = (unsigned short*)ws; ws += 256 * 256 * 2;
    unsigned short* W3Thi = (unsigned short*)ws; ws += 256 * 256 * 2;
    unsigned short* W3Tlo = (unsigned short*)ws; ws += 256 * 256 * 2;

    hipMemsetAsync(cnt, 0, (size_t)N * 8, stream);   // cnt + fill
    hipMemsetAsync(out, 0, (size_t)N * 4, stream);   // fused head accumulates

    deg_kernel <<<(E + 255) / 256, 256, 0, stream>>>(ei, cnt, E);
    dinv_kernel<<<(N + 255) / 256, 256, 0, stream>>>(cnt, dinv, N);
    scan_kernel<<<1, 1024, 0, stream>>>(cnt, roff, N);
    fill_kernel<<<(E + 255) / 256, 256, 0, stream>>>(ei, roff, fill, col, E);
    agg_kernel <<<(N + 3) / 4, 256, 0, stream>>>((const float2*)x, col, roff, dinv, (float2*)agg, N);

    wcbc_kernel<<<129, 256, 0, stream>>>(Wg, bg, W1, b1, Wc, bc);
    tsplit_kernel<<<(128 * 256 + 255) / 256, 256, 0, stream>>>(Wc, WcThi, WcTlo, 128, 256);
    tsplit_kernel<<<(256 * 256 + 255) / 256, 256, 0, stream>>>(W2, W2Thi, W2Tlo, 256, 256);
    tsplit_kernel<<<(256 * 256 + 255) / 256, 256, 0, stream>>>(W3, W3Thi, W3Tlo, 256, 256);

    dim3 g((N + 127) / 128, 2);
    gemm_mfma<128, false><<<g, 256, 0, stream>>>(agg, WcThi, WcTlo, bc, h1, nullptr, nullptr, nullptr, N);
    gemm_mfma<256, false><<<g, 256, 0, stream>>>(h1, W2Thi, W2Tlo, b2, h2, nullptr, nullptr, nullptr, N);
    gemm_mfma<256, true ><<<g, 256, 0, stream>>>(h2, W3Thi, W3Tlo, b3, h1, Wo, bo, out, N);
}

// Round 3
// 347.437 us; speedup vs baseline: 1.5543x; 1.1069x over previous
//
#include <hip/hip_runtime.h>
#include <hip/hip_bf16.h>

#define ALPHA 0.1f

using bf16x8 = __attribute__((ext_vector_type(8))) short;
using f32x4  = __attribute__((ext_vector_type(4))) float;

__device__ __forceinline__ unsigned short f2bf(float f) {
    unsigned u = __builtin_bit_cast(unsigned, f);
    u += 0x7fff + ((u >> 16) & 1);               // round-to-nearest-even
    return (unsigned short)(u >> 16);
}
__device__ __forceinline__ float bf2f(unsigned short h) {
    unsigned u = ((unsigned)h) << 16;
    return __builtin_bit_cast(float, u);
}
__device__ __forceinline__ float bflo(unsigned v) {   // low ushort as bf16
    return __builtin_bit_cast(float, v << 16);
}
__device__ __forceinline__ float bfhi(unsigned v) {   // high ushort as bf16
    return __builtin_bit_cast(float, v & 0xffff0000u);
}

// ---------------- edge preprocessing ----------------

__global__ void deg_kernel(const int* __restrict__ ei, int* __restrict__ cnt, int E) {
    int e = blockIdx.x * blockDim.x + threadIdx.x;
    if (e >= E) return;
    atomicAdd(&cnt[ei[E + e]], 1);
}

__global__ void dinv_kernel(const int* __restrict__ cnt, float* __restrict__ dinv, int N) {
    int i = blockIdx.x * blockDim.x + threadIdx.x;
    if (i >= N) return;
    dinv[i] = 1.0f / sqrtf((float)(cnt[i] + 1));   // +1 self loop
}

__global__ void scan_kernel(const int* __restrict__ cnt, int* __restrict__ row_off, int n) {
    constexpr int T = 1024;
    __shared__ int part[T];
    int tid = threadIdx.x;
    int chunk = (n + T - 1) / T;
    int lo = tid * chunk;
    int hi = lo + chunk; if (hi > n) hi = n;
    int s = 0;
    for (int i = lo; i < hi; ++i) s += cnt[i];
    part[tid] = s;
    __syncthreads();
    for (int off = 1; off < T; off <<= 1) {
        int t = (tid >= off) ? part[tid - off] : 0;
        __syncthreads();
        part[tid] += t;
        __syncthreads();
    }
    int excl = part[tid] - s;
    for (int i = lo; i < hi; ++i) { row_off[i] = excl; excl += cnt[i]; }
    if (tid == T - 1) row_off[n] = part[T - 1];
}

__global__ void fill_kernel(const int* __restrict__ ei, const int* __restrict__ row_off,
                            int* __restrict__ fill, int* __restrict__ col, int E) {
    int e = blockIdx.x * blockDim.x + threadIdx.x;
    if (e >= E) return;
    int s = ei[e], d = ei[E + e];
    int pos = atomicAdd(&fill[d], 1);
    col[row_off[d] + pos] = s;
}

// ---------------- xs = bf16(dinv[n] * x[n])  [N][128] packed as uint pairs ----------------

__global__ void xsconv_kernel(const float4* __restrict__ x4, const float* __restrict__ dinv,
                              uint2* __restrict__ xs, int total) {   // total = N*32
    int i = blockIdx.x * blockDim.x + threadIdx.x;
    if (i >= total) return;
    float di = dinv[i >> 5];
    float4 v = x4[i];
    uint2 o;
    o.x = (unsigned)f2bf(di * v.x) | ((unsigned)f2bf(di * v.y) << 16);
    o.y = (unsigned)f2bf(di * v.z) | ((unsigned)f2bf(di * v.w) << 16);
    xs[i] = o;
}

// ---------------- aggregation: one wave per node, bf16 gather, split hi/lo output ----------------

__global__ void agg_kernel(const unsigned* __restrict__ xs, const int* __restrict__ col,
                           const int* __restrict__ roff, const float* __restrict__ dinv,
                           unsigned* __restrict__ agg_hi, unsigned* __restrict__ agg_lo, int N) {
    int w = (blockIdx.x * blockDim.x + threadIdx.x) >> 6;
    int lane = threadIdx.x & 63;
    if (w >= N) return;
    float di = dinv[w];
    unsigned vself = xs[(size_t)w * 64 + lane];
    float ax = bflo(vself), ay = bfhi(vself);      // self term: di * (di*x[w])
    int s = roff[w], e = roff[w + 1];
    int j = s;
    for (; j + 4 <= e; j += 4) {
        int c0 = col[j], c1 = col[j + 1], c2 = col[j + 2], c3 = col[j + 3];
        unsigned v0 = xs[(size_t)c0 * 64 + lane];
        unsigned v1 = xs[(size_t)c1 * 64 + lane];
        unsigned v2 = xs[(size_t)c2 * 64 + lane];
        unsigned v3 = xs[(size_t)c3 * 64 + lane];
        ax += bflo(v0) + bflo(v1) + bflo(v2) + bflo(v3);
        ay += bfhi(v0) + bfhi(v1) + bfhi(v2) + bfhi(v3);
    }
    for (; j < e; ++j) {
        unsigned v = xs[(size_t)col[j] * 64 + lane];
        ax += bflo(v);
        ay += bfhi(v);
    }
    float g0 = di * ax, g1 = di * ay;
    unsigned short h0 = f2bf(g0), h1 = f2bf(g1);
    unsigned short l0 = f2bf(g0 - bf2f(h0)), l1 = f2bf(g1 - bf2f(h1));
    agg_hi[(size_t)w * 64 + lane] = (unsigned)h0 | ((unsigned)h1 << 16);
    agg_lo[(size_t)w * 64 + lane] = (unsigned)l0 | ((unsigned)l1 << 16);
}

// ---------------- fold W_gcn@W1 -> Wc [128,256], bc = b_gcn@W1 + b1 ----------------

__global__ void wcbc_kernel(const float* __restrict__ Wg, const float* __restrict__ bg,
                            const float* __restrict__ W1, const float* __restrict__ b1,
                            float* __restrict__ Wc, float* __restrict__ bc) {
    int n = threadIdx.x;
    int m = blockIdx.x;
    if (m < 128) {
        float acc = 0.f;
#pragma unroll 8
        for (int k = 0; k < 512; ++k) acc += Wg[m * 512 + k] * W1[k * 256 + n];
        Wc[m * 256 + n] = acc;
    } else {
        float acc = b1[n];
#pragma unroll 8
        for (int k = 0; k < 512; ++k) acc += bg[k] * W1[k * 256 + n];
        bc[n] = acc;
    }
}

// ---------------- transpose+split weights: W[K][Nn] fp32 -> Wt_hi/lo [Nn][K] bf16 ----------------

__global__ void tsplit_kernel(const float* __restrict__ W, unsigned short* __restrict__ hi,
                              unsigned short* __restrict__ lo, int K, int Nn) {
    int idx = blockIdx.x * blockDim.x + threadIdx.x;
    if (idx >= K * Nn) return;
    int n = idx / K, k = idx - n * K;
    float v = W[k * Nn + n];
    unsigned short h = f2bf(v);
    hi[idx] = h;
    lo[idx] = f2bf(v - bf2f(h));
}

// ---------------- split-bf16 MFMA GEMM: C = leaky(A[M,K]@B[K,256] + bias) ----------------
// A pre-split into AHi/ALo bf16 [M][K]; 3 passes: ah*bh + ah*bl + al*bh
// block = 256 thr = 4 waves (2x2), tile 128x128, wave tile 64x64 = 4x4 frags of 16x16x32

template <int KTOT, bool OUT>
__global__ __launch_bounds__(256) void gemm_mfma(
    const unsigned short* __restrict__ AHi, const unsigned short* __restrict__ ALo,
    const unsigned short* __restrict__ BtHi, const unsigned short* __restrict__ BtLo,
    const float* __restrict__ bias,
    unsigned short* __restrict__ CHi, unsigned short* __restrict__ CLo,
    const float* __restrict__ wo, const float* __restrict__ bo,
    float* __restrict__ outv, int M)
{
    constexpr int BM = 128, BN = 128, BK = 32, LDT = BK + 8;   // +8 bf16 pad
    __shared__ unsigned short Ahi[BM][LDT], Alo[BM][LDT], Bhi[BN][LDT], Blo[BN][LDT];

    const int tid  = threadIdx.x;
    const int lane = tid & 63;
    const int wid  = tid >> 6;
    const int wrow = wid >> 1, wcol = wid & 1;
    const int m0 = blockIdx.x * BM, n0 = blockIdx.y * BN;
    const int l15 = lane & 15, l4 = lane >> 4;
    const int koff = l4 * 8;

    f32x4 acc[4][4] = {};

    for (int k0 = 0; k0 < KTOT; k0 += BK) {
        // ---- stage A: pure int4 copies (4 threads/row, 16B each) ----
#pragma unroll
        for (int i = 0; i < 2; ++i) {
            int lin = tid + i * 256;
            int m = lin >> 2, c = lin & 3;
            int gm = m0 + m; if (gm >= M) gm = M - 1;
            size_t ga = (size_t)gm * KTOT + k0 + c * 8;
            *reinterpret_cast<int4*>(&Ahi[m][c * 8]) = *reinterpret_cast<const int4*>(&AHi[ga]);
            *reinterpret_cast<int4*>(&Alo[m][c * 8]) = *reinterpret_cast<const int4*>(&ALo[ga]);
        }
        // ---- stage B ----
#pragma unroll
        for (int i = 0; i < 2; ++i) {
            int lin = tid + i * 256;
            int n = lin >> 2, s = lin & 3;
            size_t gb = (size_t)(n0 + n) * KTOT + k0 + s * 8;
            *reinterpret_cast<int4*>(&Bhi[n][s * 8]) = *reinterpret_cast<const int4*>(&BtHi[gb]);
            *reinterpret_cast<int4*>(&Blo[n][s * 8]) = *reinterpret_cast<const int4*>(&BtLo[gb]);
        }
        __syncthreads();

        bf16x8 af[4], al[4], bh[4], bl[4];
#pragma unroll
        for (int mi = 0; mi < 4; ++mi)
            af[mi] = *reinterpret_cast<const bf16x8*>(&Ahi[wrow * 64 + mi * 16 + l15][koff]);
#pragma unroll
        for (int ni = 0; ni < 4; ++ni)
            bh[ni] = *reinterpret_cast<const bf16x8*>(&Bhi[wcol * 64 + ni * 16 + l15][koff]);
#pragma unroll
        for (int mi = 0; mi < 4; ++mi)
#pragma unroll
            for (int ni = 0; ni < 4; ++ni)
                acc[mi][ni] = __builtin_amdgcn_mfma_f32_16x16x32_bf16(af[mi], bh[ni], acc[mi][ni], 0, 0, 0);
#pragma unroll
        for (int ni = 0; ni < 4; ++ni)
            bl[ni] = *reinterpret_cast<const bf16x8*>(&Blo[wcol * 64 + ni * 16 + l15][koff]);
#pragma unroll
        for (int mi = 0; mi < 4; ++mi)
#pragma unroll
            for (int ni = 0; ni < 4; ++ni)
                acc[mi][ni] = __builtin_amdgcn_mfma_f32_16x16x32_bf16(af[mi], bl[ni], acc[mi][ni], 0, 0, 0);
#pragma unroll
        for (int mi = 0; mi < 4; ++mi)
            al[mi] = *reinterpret_cast<const bf16x8*>(&Alo[wrow * 64 + mi * 16 + l15][koff]);
#pragma unroll
        for (int mi = 0; mi < 4; ++mi)
#pragma unroll
            for (int ni = 0; ni < 4; ++ni)
                acc[mi][ni] = __builtin_amdgcn_mfma_f32_16x16x32_bf16(al[mi], bh[ni], acc[mi][ni], 0, 0, 0);
        __syncthreads();
    }

    // ---- epilogue ----  C/D frag: col = lane&15, row = (lane>>4)*4 + reg  [m89]
    if (!OUT) {
#pragma unroll
        for (int mi = 0; mi < 4; ++mi) {
#pragma unroll
            for (int r = 0; r < 4; ++r) {
                int gm = m0 + wrow * 64 + mi * 16 + l4 * 4 + r;
                if (gm >= M) continue;
#pragma unroll
                for (int ni = 0; ni < 4; ++ni) {
                    int gn = n0 + wcol * 64 + ni * 16 + l15;
                    float v = acc[mi][ni][r] + bias[gn];
                    v = v > 0.f ? v : ALPHA * v;
                    unsigned short h = f2bf(v);
                    CHi[(size_t)gm * 256 + gn] = h;
                    CLo[(size_t)gm * 256 + gn] = f2bf(v - bf2f(h));
                }
            }
        }
    } else {
        // fused output head: out[m] = sum_n leaky(h3[m,n]) * wo[n]  (+ bo once)
        float bn[4], wn[4];
#pragma unroll
        for (int ni = 0; ni < 4; ++ni) {
            int gn = n0 + wcol * 64 + ni * 16 + l15;
            bn[ni] = bias[gn];
            wn[ni] = wo[gn];
        }
        float badd = (n0 == 0) ? bo[0] : 0.f;
#pragma unroll
        for (int mi = 0; mi < 4; ++mi) {
#pragma unroll
            for (int r = 0; r < 4; ++r) {
                float p = 0.f;
#pragma unroll
                for (int ni = 0; ni < 4; ++ni) {
                    float v = acc[mi][ni][r] + bn[ni];
                    v = v > 0.f ? v : ALPHA * v;
                    p += v * wn[ni];
                }
#pragma unroll
                for (int off = 1; off < 16; off <<= 1) p += __shfl_xor(p, off, 16);
                int gm = m0 + wrow * 64 + mi * 16 + l4 * 4 + r;
                if (l15 == 0 && gm < M) atomicAdd(&outv[gm], p + badd);
            }
        }
    }
}

// ---------------- launch ----------------

extern "C" void kernel_launch(void* const* d_in, const int* in_sizes, int n_in,
                              void* d_out, int out_size, void* d_ws, size_t ws_size,
                              hipStream_t stream) {
    const float* x  = (const float*)d_in[0];
    const int*   ei = (const int*)d_in[1];
    const float* Wg = (const float*)d_in[2];
    const float* bg = (const float*)d_in[3];
    const float* W1 = (const float*)d_in[4];
    const float* b1 = (const float*)d_in[5];
    const float* W2 = (const float*)d_in[6];
    const float* b2 = (const float*)d_in[7];
    const float* W3 = (const float*)d_in[8];
    const float* b3 = (const float*)d_in[9];
    const float* Wo = (const float*)d_in[10];
    const float* bo = (const float*)d_in[11];
    float* out = (float*)d_out;

    const int N = in_sizes[0] / 128;   // 50000
    const int E = in_sizes[1] / 2;     // 800000

    char* ws = (char*)d_ws;
    unsigned* xs     = (unsigned*)ws; ws += (size_t)N * 64 * 4;     // bf16 dinv*x table
    unsigned* aggHi  = (unsigned*)ws; ws += (size_t)N * 64 * 4;
    unsigned* aggLo  = (unsigned*)ws; ws += (size_t)N * 64 * 4;
    unsigned short* h1Hi = (unsigned short*)ws; ws += (size_t)N * 256 * 2;
    unsigned short* h1Lo = (unsigned short*)ws; ws += (size_t)N * 256 * 2;
    unsigned short* h2Hi = (unsigned short*)ws; ws += (size_t)N * 256 * 2;
    unsigned short* h2Lo = (unsigned short*)ws; ws += (size_t)N * 256 * 2;
    int* col   = (int*)ws;    ws += (size_t)E * 4;
    int* cnt   = (int*)ws;    ws += (size_t)N * 4;
    int* fill  = (int*)ws;    ws += (size_t)N * 4;   // cnt & fill contiguous -> one memset
    int* roff  = (int*)ws;    ws += (size_t)(N + 64) * 4;
    float* dinv= (float*)ws;  ws += (size_t)N * 4;
    float* Wc  = (float*)ws;  ws += 128 * 256 * 4;
    float* bc  = (float*)ws;  ws += 256 * 4;
    unsigned short* WcThi = (unsigned short*)ws; ws += 256 * 128 * 2;
    unsigned short* WcTlo = (unsigned short*)ws; ws += 256 * 128 * 2;
    unsigned short* W2Thi = (unsigned short*)ws; ws += 256 * 256 * 2;
    unsigned short* W2Tlo = (unsigned short*)ws; ws += 256 * 256 * 2;
    unsigned short* W3Thi = (unsigned short*)ws; ws += 256 * 256 * 2;
    unsigned short* W3Tlo = (unsigned short*)ws; ws += 256 * 256 * 2;

    hipMemsetAsync(cnt, 0, (size_t)N * 8, stream);   // cnt + fill
    hipMemsetAsync(out, 0, (size_t)N * 4, stream);   // fused head accumulates

    deg_kernel <<<(E + 255) / 256, 256, 0, stream>>>(ei, cnt, E);
    dinv_kernel<<<(N + 255) / 256, 256, 0, stream>>>(cnt, dinv, N);
    scan_kernel<<<1, 1024, 0, stream>>>(cnt, roff, N);
    fill_kernel<<<(E + 255) / 256, 256, 0, stream>>>(ei, roff, fill, col, E);
    xsconv_kernel<<<(N * 32 + 255) / 256, 256, 0, stream>>>((const float4*)x, dinv, (uint2*)xs, N * 32);
    agg_kernel <<<(N + 3) / 4, 256, 0, stream>>>(xs, col, roff, dinv, aggHi, aggLo, N);

    wcbc_kernel<<<129, 256, 0, stream>>>(Wg, bg, W1, b1, Wc, bc);
    tsplit_kernel<<<(128 * 256 + 255) / 256, 256, 0, stream>>>(Wc, WcThi, WcTlo, 128, 256);
    tsplit_kernel<<<(256 * 256 + 255) / 256, 256, 0, stream>>>(W2, W2Thi, W2Tlo, 256, 256);
    tsplit_kernel<<<(256 * 256 + 255) / 256, 256, 0, stream>>>(W3, W3Thi, W3Tlo, 256, 256);

    dim3 g((N + 127) / 128, 2);
    gemm_mfma<128, false><<<g, 256, 0, stream>>>((const unsigned short*)aggHi, (const unsigned short*)aggLo,
                                                 WcThi, WcTlo, bc, h1Hi, h1Lo, nullptr, nullptr, nullptr, N);
    gemm_mfma<256, false><<<g, 256, 0, stream>>>(h1Hi, h1Lo, W2Thi, W2Tlo, b2, h2Hi, h2Lo,
                                                 nullptr, nullptr, nullptr, N);
    gemm_mfma<256, true ><<<g, 256, 0, stream>>>(h2Hi, h2Lo, W3Thi, W3Tlo, b3, nullptr, nullptr,
                                                 Wo, bo, out, N);
}

// Round 4
// 283.049 us; speedup vs baseline: 1.9079x; 1.2275x over previous
//
#include <hip/hip_runtime.h>
#include <hip/hip_bf16.h>

#define ALPHA 0.1f

using bf16x8 = __attribute__((ext_vector_type(8))) short;
using f32x4  = __attribute__((ext_vector_type(4))) float;

__device__ __forceinline__ unsigned short f2bf(float f) {
    unsigned u = __builtin_bit_cast(unsigned, f);
    u += 0x7fff + ((u >> 16) & 1);               // round-to-nearest-even
    return (unsigned short)(u >> 16);
}
__device__ __forceinline__ float bf2f(unsigned short h) {
    unsigned u = ((unsigned)h) << 16;
    return __builtin_bit_cast(float, u);
}
__device__ __forceinline__ float bflo(unsigned v) {   // low ushort as bf16
    return __builtin_bit_cast(float, v << 16);
}
__device__ __forceinline__ float bfhi(unsigned v) {   // high ushort as bf16
    return __builtin_bit_cast(float, v & 0xffff0000u);
}

// ---------------- edge preprocessing ----------------

__global__ void deg_kernel(const int* __restrict__ ei, int* __restrict__ cnt, int E) {
    int e = blockIdx.x * blockDim.x + threadIdx.x;
    if (e >= E) return;
    atomicAdd(&cnt[ei[E + e]], 1);
}

// per-wave atomic segment allocator + dinv  (replaces the serial scan: segments
// need only be contiguous per node, not ordered -> wave prefix + 1 atomic/wave)
__global__ void alloc_kernel(const int* __restrict__ cnt, int* __restrict__ roff,
                             float* __restrict__ dinv, int* __restrict__ cursor, int N) {
    int i = blockIdx.x * blockDim.x + threadIdx.x;
    int lane = threadIdx.x & 63;
    int c = (i < N) ? cnt[i] : 0;
    if (i < N) dinv[i] = 1.0f / sqrtf((float)(c + 1));   // +1 self loop
    int pre = c;
#pragma unroll
    for (int off = 1; off < 64; off <<= 1) {
        int t = __shfl_up(pre, off, 64);
        if (lane >= off) pre += t;
    }
    int total = __shfl(pre, 63, 64);
    int base = 0;
    if (lane == 0) base = atomicAdd(cursor, total);
    base = __shfl(base, 0, 64);
    if (i < N) roff[i] = base + pre - c;
}

__global__ void fill_kernel(const int* __restrict__ ei, const int* __restrict__ roff,
                            int* __restrict__ fill, int* __restrict__ col, int E) {
    int e = blockIdx.x * blockDim.x + threadIdx.x;
    if (e >= E) return;
    int s = ei[e], d = ei[E + e];
    int pos = atomicAdd(&fill[d], 1);
    col[roff[d] + pos] = s;
}

// ---------------- xs = bf16(dinv[n] * x[n])  [N][128] packed as uint pairs ----------------

__global__ void xsconv_kernel(const float4* __restrict__ x4, const float* __restrict__ dinv,
                              uint2* __restrict__ xs, int total) {   // total = N*32
    int i = blockIdx.x * blockDim.x + threadIdx.x;
    if (i >= total) return;
    float di = dinv[i >> 5];
    float4 v = x4[i];
    uint2 o;
    o.x = (unsigned)f2bf(di * v.x) | ((unsigned)f2bf(di * v.y) << 16);
    o.y = (unsigned)f2bf(di * v.z) | ((unsigned)f2bf(di * v.w) << 16);
    xs[i] = o;
}

// ---------------- aggregation: one wave per node, bf16 gather, split hi/lo output ----------------

__global__ void agg_kernel(const unsigned* __restrict__ xs, const int* __restrict__ col,
                           const int* __restrict__ roff, const int* __restrict__ cnt,
                           const float* __restrict__ dinv,
                           unsigned* __restrict__ agg_hi, unsigned* __restrict__ agg_lo, int N) {
    int w = (blockIdx.x * blockDim.x + threadIdx.x) >> 6;
    int lane = threadIdx.x & 63;
    if (w >= N) return;
    float di = dinv[w];
    unsigned vself = xs[(size_t)w * 64 + lane];
    float ax = bflo(vself), ay = bfhi(vself);      // self term: di * (di*x[w])
    int s = roff[w], e = s + cnt[w];
    int j = s;
    for (; j + 4 <= e; j += 4) {
        int c0 = col[j], c1 = col[j + 1], c2 = col[j + 2], c3 = col[j + 3];
        unsigned v0 = xs[(size_t)c0 * 64 + lane];
        unsigned v1 = xs[(size_t)c1 * 64 + lane];
        unsigned v2 = xs[(size_t)c2 * 64 + lane];
        unsigned v3 = xs[(size_t)c3 * 64 + lane];
        ax += bflo(v0) + bflo(v1) + bflo(v2) + bflo(v3);
        ay += bfhi(v0) + bfhi(v1) + bfhi(v2) + bfhi(v3);
    }
    for (; j < e; ++j) {
        unsigned v = xs[(size_t)col[j] * 64 + lane];
        ax += bflo(v);
        ay += bfhi(v);
    }
    float g0 = di * ax, g1 = di * ay;
    unsigned short h0 = f2bf(g0), h1 = f2bf(g1);
    unsigned short l0 = f2bf(g0 - bf2f(h0)), l1 = f2bf(g1 - bf2f(h1));
    agg_hi[(size_t)w * 64 + lane] = (unsigned)h0 | ((unsigned)h1 << 16);
    agg_lo[(size_t)w * 64 + lane] = (unsigned)l0 | ((unsigned)l1 << 16);
}

// ---------------- fold W_gcn@W1 -> Wc [128,256], bc = b_gcn@W1 + b1 ----------------

__global__ void wcbc_kernel(const float* __restrict__ Wg, const float* __restrict__ bg,
                            const float* __restrict__ W1, const float* __restrict__ b1,
                            float* __restrict__ Wc, float* __restrict__ bc) {
    int n = threadIdx.x;
    int m = blockIdx.x;
    if (m < 128) {
        float acc = 0.f;
#pragma unroll 8
        for (int k = 0; k < 512; ++k) acc += Wg[m * 512 + k] * W1[k * 256 + n];
        Wc[m * 256 + n] = acc;
    } else {
        float acc = b1[n];
#pragma unroll 8
        for (int k = 0; k < 512; ++k) acc += bg[k] * W1[k * 256 + n];
        bc[n] = acc;
    }
}

// ---------------- transpose+split weights: W[K][Nn] fp32 -> Wt_hi/lo [Nn][K] bf16 ----------------

__global__ void tsplit_kernel(const float* __restrict__ W, unsigned short* __restrict__ hi,
                              unsigned short* __restrict__ lo, int K, int Nn) {
    int idx = blockIdx.x * blockDim.x + threadIdx.x;
    if (idx >= K * Nn) return;
    int n = idx / K, k = idx - n * K;
    float v = W[k * Nn + n];
    unsigned short h = f2bf(v);
    hi[idx] = h;
    lo[idx] = f2bf(v - bf2f(h));
}

// ---------------- split-bf16 MFMA GEMM: C = leaky(A[M,K]@B[K,256] + bias) ----------------
// A pre-split into AHi/ALo bf16 [M][K]; 3 passes: ah*bh + ah*bl + al*bh
// block = 256 thr = 4 waves (2x2), tile 128x128, wave tile 64x64 = 4x4 frags of 16x16x32

template <int KTOT, bool OUT>
__global__ __launch_bounds__(256) void gemm_mfma(
    const unsigned short* __restrict__ AHi, const unsigned short* __restrict__ ALo,
    const unsigned short* __restrict__ BtHi, const unsigned short* __restrict__ BtLo,
    const float* __restrict__ bias,
    unsigned short* __restrict__ CHi, unsigned short* __restrict__ CLo,
    const float* __restrict__ wo, const float* __restrict__ bo,
    float* __restrict__ outv, int M)
{
    constexpr int BM = 128, BN = 128, BK = 32, LDT = BK + 8;   // +8 bf16 pad
    __shared__ unsigned short Ahi[BM][LDT], Alo[BM][LDT], Bhi[BN][LDT], Blo[BN][LDT];

    const int tid  = threadIdx.x;
    const int lane = tid & 63;
    const int wid  = tid >> 6;
    const int wrow = wid >> 1, wcol = wid & 1;
    const int m0 = blockIdx.x * BM, n0 = blockIdx.y * BN;
    const int l15 = lane & 15, l4 = lane >> 4;
    const int koff = l4 * 8;

    f32x4 acc[4][4] = {};

    for (int k0 = 0; k0 < KTOT; k0 += BK) {
        // ---- stage A: pure int4 copies (4 threads/row, 16B each) ----
#pragma unroll
        for (int i = 0; i < 2; ++i) {
            int lin = tid + i * 256;
            int m = lin >> 2, c = lin & 3;
            int gm = m0 + m; if (gm >= M) gm = M - 1;
            size_t ga = (size_t)gm * KTOT + k0 + c * 8;
            *reinterpret_cast<int4*>(&Ahi[m][c * 8]) = *reinterpret_cast<const int4*>(&AHi[ga]);
            *reinterpret_cast<int4*>(&Alo[m][c * 8]) = *reinterpret_cast<const int4*>(&ALo[ga]);
        }
        // ---- stage B ----
#pragma unroll
        for (int i = 0; i < 2; ++i) {
            int lin = tid + i * 256;
            int n = lin >> 2, s = lin & 3;
            size_t gb = (size_t)(n0 + n) * KTOT + k0 + s * 8;
            *reinterpret_cast<int4*>(&Bhi[n][s * 8]) = *reinterpret_cast<const int4*>(&BtHi[gb]);
            *reinterpret_cast<int4*>(&Blo[n][s * 8]) = *reinterpret_cast<const int4*>(&BtLo[gb]);
        }
        __syncthreads();

        bf16x8 af[4], al[4], bh[4], bl[4];
#pragma unroll
        for (int mi = 0; mi < 4; ++mi)
            af[mi] = *reinterpret_cast<const bf16x8*>(&Ahi[wrow * 64 + mi * 16 + l15][koff]);
#pragma unroll
        for (int ni = 0; ni < 4; ++ni)
            bh[ni] = *reinterpret_cast<const bf16x8*>(&Bhi[wcol * 64 + ni * 16 + l15][koff]);
#pragma unroll
        for (int mi = 0; mi < 4; ++mi)
#pragma unroll
            for (int ni = 0; ni < 4; ++ni)
                acc[mi][ni] = __builtin_amdgcn_mfma_f32_16x16x32_bf16(af[mi], bh[ni], acc[mi][ni], 0, 0, 0);
#pragma unroll
        for (int ni = 0; ni < 4; ++ni)
            bl[ni] = *reinterpret_cast<const bf16x8*>(&Blo[wcol * 64 + ni * 16 + l15][koff]);
#pragma unroll
        for (int mi = 0; mi < 4; ++mi)
#pragma unroll
            for (int ni = 0; ni < 4; ++ni)
                acc[mi][ni] = __builtin_amdgcn_mfma_f32_16x16x32_bf16(af[mi], bl[ni], acc[mi][ni], 0, 0, 0);
#pragma unroll
        for (int mi = 0; mi < 4; ++mi)
            al[mi] = *reinterpret_cast<const bf16x8*>(&Alo[wrow * 64 + mi * 16 + l15][koff]);
#pragma unroll
        for (int mi = 0; mi < 4; ++mi)
#pragma unroll
            for (int ni = 0; ni < 4; ++ni)
                acc[mi][ni] = __builtin_amdgcn_mfma_f32_16x16x32_bf16(al[mi], bh[ni], acc[mi][ni], 0, 0, 0);
        __syncthreads();
    }

    // ---- epilogue ----  C/D frag: col = lane&15, row = (lane>>4)*4 + reg  [m89]
    if (!OUT) {
#pragma unroll
        for (int mi = 0; mi < 4; ++mi) {
#pragma unroll
            for (int r = 0; r < 4; ++r) {
                int gm = m0 + wrow * 64 + mi * 16 + l4 * 4 + r;
                if (gm >= M) continue;
#pragma unroll
                for (int ni = 0; ni < 4; ++ni) {
                    int gn = n0 + wcol * 64 + ni * 16 + l15;
                    float v = acc[mi][ni][r] + bias[gn];
                    v = v > 0.f ? v : ALPHA * v;
                    unsigned short h = f2bf(v);
                    CHi[(size_t)gm * 256 + gn] = h;
                    CLo[(size_t)gm * 256 + gn] = f2bf(v - bf2f(h));
                }
            }
        }
    } else {
        // fused output head: out[m] = sum_n leaky(h3[m,n]) * wo[n]  (+ bo once)
        float bn[4], wn[4];
#pragma unroll
        for (int ni = 0; ni < 4; ++ni) {
            int gn = n0 + wcol * 64 + ni * 16 + l15;
            bn[ni] = bias[gn];
            wn[ni] = wo[gn];
        }
        float badd = (n0 == 0) ? bo[0] : 0.f;
#pragma unroll
        for (int mi = 0; mi < 4; ++mi) {
#pragma unroll
            for (int r = 0; r < 4; ++r) {
                float p = 0.f;
#pragma unroll
                for (int ni = 0; ni < 4; ++ni) {
                    float v = acc[mi][ni][r] + bn[ni];
                    v = v > 0.f ? v : ALPHA * v;
                    p += v * wn[ni];
                }
#pragma unroll
                for (int off = 1; off < 16; off <<= 1) p += __shfl_xor(p, off, 16);
                int gm = m0 + wrow * 64 + mi * 16 + l4 * 4 + r;
                if (l15 == 0 && gm < M) atomicAdd(&outv[gm], p + badd);
            }
        }
    }
}

// ---------------- launch ----------------

extern "C" void kernel_launch(void* const* d_in, const int* in_sizes, int n_in,
                              void* d_out, int out_size, void* d_ws, size_t ws_size,
                              hipStream_t stream) {
    const float* x  = (const float*)d_in[0];
    const int*   ei = (const int*)d_in[1];
    const float* Wg = (const float*)d_in[2];
    const float* bg = (const float*)d_in[3];
    const float* W1 = (const float*)d_in[4];
    const float* b1 = (const float*)d_in[5];
    const float* W2 = (const float*)d_in[6];
    const float* b2 = (const float*)d_in[7];
    const float* W3 = (const float*)d_in[8];
    const float* b3 = (const float*)d_in[9];
    const float* Wo = (const float*)d_in[10];
    const float* bo = (const float*)d_in[11];
    float* out = (float*)d_out;

    const int N = in_sizes[0] / 128;   // 50000
    const int E = in_sizes[1] / 2;     // 800000

    char* ws = (char*)d_ws;
    unsigned* xs     = (unsigned*)ws; ws += (size_t)N * 64 * 4;     // bf16 dinv*x table
    unsigned* aggHi  = (unsigned*)ws; ws += (size_t)N * 64 * 4;
    unsigned* aggLo  = (unsigned*)ws; ws += (size_t)N * 64 * 4;
    unsigned short* h1Hi = (unsigned short*)ws; ws += (size_t)N * 256 * 2;
    unsigned short* h1Lo = (unsigned short*)ws; ws += (size_t)N * 256 * 2;
    unsigned short* h2Hi = (unsigned short*)ws; ws += (size_t)N * 256 * 2;
    unsigned short* h2Lo = (unsigned short*)ws; ws += (size_t)N * 256 * 2;
    int* col   = (int*)ws;    ws += (size_t)E * 4;
    int* cnt   = (int*)ws;    ws += (size_t)N * 4;
    int* fill  = (int*)ws;    ws += (size_t)N * 4;   // cnt & fill & cursor contiguous -> one memset
    int* cursor= (int*)ws;    ws += 64;
    int* roff  = (int*)ws;    ws += (size_t)(N + 64) * 4;
    float* dinv= (float*)ws;  ws += (size_t)N * 4;
    float* Wc  = (float*)ws;  ws += 128 * 256 * 4;
    float* bc  = (float*)ws;  ws += 256 * 4;
    unsigned short* WcThi = (unsigned short*)ws; ws += 256 * 128 * 2;
    unsigned short* WcTlo = (unsigned short*)ws; ws += 256 * 128 * 2;
    unsigned short* W2Thi = (unsigned short*)ws; ws += 256 * 256 * 2;
    unsigned short* W2Tlo = (unsigned short*)ws; ws += 256 * 256 * 2;
    unsigned short* W3Thi = (unsigned short*)ws; ws += 256 * 256 * 2;
    unsigned short* W3Tlo = (unsigned short*)ws; ws += 256 * 256 * 2;

    hipMemsetAsync(cnt, 0, (size_t)N * 8 + 64, stream);   // cnt + fill + cursor
    hipMemsetAsync(out, 0, (size_t)N * 4, stream);        // fused head accumulates

    deg_kernel  <<<(E + 255) / 256, 256, 0, stream>>>(ei, cnt, E);
    alloc_kernel<<<(N + 255) / 256, 256, 0, stream>>>(cnt, roff, dinv, cursor, N);
    fill_kernel <<<(E + 255) / 256, 256, 0, stream>>>(ei, roff, fill, col, E);
    xsconv_kernel<<<(N * 32 + 255) / 256, 256, 0, stream>>>((const float4*)x, dinv, (uint2*)xs, N * 32);
    agg_kernel  <<<(N + 3) / 4, 256, 0, stream>>>(xs, col, roff, cnt, dinv, aggHi, aggLo, N);

    wcbc_kernel<<<129, 256, 0, stream>>>(Wg, bg, W1, b1, Wc, bc);
    tsplit_kernel<<<(128 * 256 + 255) / 256, 256, 0, stream>>>(Wc, WcThi, WcTlo, 128, 256);
    tsplit_kernel<<<(256 * 256 + 255) / 256, 256, 0, stream>>>(W2, W2Thi, W2Tlo, 256, 256);
    tsplit_kernel<<<(256 * 256 + 255) / 256, 256, 0, stream>>>(W3, W3Thi, W3Tlo, 256, 256);

    dim3 g((N + 127) / 128, 2);
    gemm_mfma<128, false><<<g, 256, 0, stream>>>((const unsigned short*)aggHi, (const unsigned short*)aggLo,
                                                 WcThi, WcTlo, bc, h1Hi, h1Lo, nullptr, nullptr, nullptr, N);
    gemm_mfma<256, false><<<g, 256, 0, stream>>>(h1Hi, h1Lo, W2Thi, W2Tlo, b2, h2Hi, h2Lo,
                                                 nullptr, nullptr, nullptr, N);
    gemm_mfma<256, true ><<<g, 256, 0, stream>>>(h2Hi, h2Lo, W3Thi, W3Tlo, b3, nullptr, nullptr,
                                                 Wo, bo, out, N);
}